// Round 9
// baseline (129.397 us; speedup 1.0000x reference)
//
#include <hip/hip_runtime.h>
#include <hip/hip_fp16.h>

// Problem constants (B,C,D,H,W) = (2,4,96,160,160)
#define NB 2
#define NC 4
#define ND 96
#define NH 160
#define NW 160

// Math (verified exact rounds 1-8): sy == sz (identical 2D 3x3 kernels),
// depth padding adds only zero slices, sobel(p)-sobel(t) = sobel(q) with
// q = softmax(pred) - onehot(target):
//   loss = sum(gx^2 + 2*gy^2) * SCALE
// separable: d = q[x+1]-q[x-1], s = q[x-1]+2q[x]+q[x+1],
//            gx = d[y-1]+2d[y]+d[y+1], gy = s[y+1]-s[y-1].
//
// Perf history:
//  r4/r5: __launch_bounds__(256,6) VGPR cap -> 128 MB scratch spill. NEVER
//         add an occupancy floor here.
//  r2..r6: dur == #same-address-atomicAdds x ~20ns -> cross-XCD serialization.
//         Fixed r7: per-block partial stores to d_ws + tiny reduce kernel.
//  r8: fp16-packed LDS class-pair planes, conflict-free b128/b32, 13 KB LDS.
//  r9 (this): blocks were latency-bound (3840 short blocks x 1 uncovered
//         ~900cyc load latency, ~2.5 blocks/CU overlap). Now each block runs
//         M=5 bands software-pipelined with double-buffered LDS: loads for
//         band i+1 fly while band i computes. 768 blocks, 768 partials.
constexpr int TH    = 8;               // output rows per band
constexpr int SR    = TH + 2;          // staged rows (vertical halo)
constexpr int NBAND = NH / TH;         // 20 bands per slice
constexpr int M     = 5;               // bands per block (pipelined)
constexpr int SEG   = NBAND / M;       // 4 segments per slice
constexpr int NSLOT = SR * NW / 4;     // 400 4-pixel staging slots per band
constexpr int PCELL = SR * NW;         // 1600 px cells per plane
constexpr int ZCELL = PCELL;           // always-zero guard cell (x-boundary)
constexpr int NPART = NB * ND * SEG;   // 768 partials
constexpr float SCALE = 1.0f / (2.0f * 98.0f * 162.0f * 162.0f * 4.0f);

__device__ __forceinline__ __half2 ld_h2(const unsigned int* p, int i) {
    return __builtin_bit_cast(__half2, p[i]);
}

// One pixel: softmax over 4 class logits minus onehot(target), packed as
// two half2 (classes 01 -> a, classes 23 -> b).
__device__ __forceinline__ void qcalc(float p0, float p1, float p2, float p3,
                                      int t, bool valid,
                                      unsigned int& ha, unsigned int& hb) {
    float q0 = 0.f, q1 = 0.f, q2 = 0.f, q3 = 0.f;
    if (valid) {
        const float m  = fmaxf(fmaxf(p0, p1), fmaxf(p2, p3));
        const float e0 = __expf(p0 - m);
        const float e1 = __expf(p1 - m);
        const float e2 = __expf(p2 - m);
        const float e3 = __expf(p3 - m);
        const float inv = 1.0f / (e0 + e1 + e2 + e3);
        q0 = e0 * inv - (t == 0 ? 1.f : 0.f);
        q1 = e1 * inv - (t == 1 ? 1.f : 0.f);
        q2 = e2 * inv - (t == 2 ? 1.f : 0.f);
        q3 = e3 * inv - (t == 3 ? 1.f : 0.f);
    }
    ha = __builtin_bit_cast(unsigned int, __floats2half2_rn(q0, q1));
    hb = __builtin_bit_cast(unsigned int, __floats2half2_rn(q2, q3));
}

// One band's in-flight global loads (named members only; no dynamic indexing
// -> SROA keeps everything in registers).
struct Regs {
    float4 a0, a1, a2, a3; int4 ta; bool vA;
    float4 b0, b1, b2, b3; int4 tb; bool vB;
};

__global__ __launch_bounds__(256) void boundary_loss_kernel(
    const float* __restrict__ pred,   // (B,C,D,H,W) f32
    const int*   __restrict__ target, // (B,D,H,W) i32
    float* __restrict__ part)         // NPART per-block partials
{
    __shared__ unsigned int pa[2][PCELL + 4];  // classes 0,1 packed half2
    __shared__ unsigned int pb[2][PCELL + 4];  // classes 2,3 packed half2
    __shared__ float wsum[4];

    const int tid   = threadIdx.x;
    const int slice = blockIdx.y;     // b*ND + d
    const int b     = slice / ND;
    const int d     = slice - b * ND;
    const int yseg  = blockIdx.x * (M * TH);   // first output row of segment

    const size_t cs4   = (size_t)ND * NH * NW / 4;   // class stride in float4
    const size_t pbase = ((size_t)b * NC * ND + d) * (size_t)(NH * NW);
    const size_t tbase = ((size_t)b * ND + d) * (size_t)(NH * NW);

    // y0-independent slot mapping: slot A = tid, slot B = tid+256 (tid<144)
    const int  rA   = tid / 40;
    const int  cA   = tid - rA * 40;
    const int  sB   = tid + 256;
    const bool hasB = (sB < NSLOT);
    const int  rB   = sB / 40;
    const int  cB   = sB - rB * 40;
    const int  cBs  = hasB ? cB : 0;

    auto load_band = [&](int y0) {
        Regs r;
        const int gyA  = y0 - 1 + rA;
        r.vA = (gyA >= 0) && (gyA < NH);
        const int gyAc = min(max(gyA, 0), NH - 1);
        const float4* ppA = (const float4*)(pred + pbase + (size_t)gyAc * NW) + cA;
        r.a0 = ppA[0]; r.a1 = ppA[cs4]; r.a2 = ppA[2 * cs4]; r.a3 = ppA[3 * cs4];
        r.ta = ((const int4*)(target + tbase + (size_t)gyAc * NW))[cA];

        const int gyB  = y0 - 1 + rB;
        r.vB = hasB && (gyB >= 0) && (gyB < NH);
        const int gyBc = hasB ? min(max(gyB, 0), NH - 1) : 0;
        const float4* ppB = (const float4*)(pred + pbase + (size_t)gyBc * NW) + cBs;
        r.b0 = ppB[0]; r.b1 = ppB[cs4]; r.b2 = ppB[2 * cs4]; r.b3 = ppB[3 * cs4];
        r.tb = ((const int4*)(target + tbase + (size_t)gyBc * NW))[cBs];
        return r;
    };

    auto stage_band = [&](const Regs& r, unsigned int* Pa, unsigned int* Pb) {
        uint4 wa, wb;
        qcalc(r.a0.x, r.a1.x, r.a2.x, r.a3.x, r.ta.x, r.vA, wa.x, wb.x);
        qcalc(r.a0.y, r.a1.y, r.a2.y, r.a3.y, r.ta.y, r.vA, wa.y, wb.y);
        qcalc(r.a0.z, r.a1.z, r.a2.z, r.a3.z, r.ta.z, r.vA, wa.z, wb.z);
        qcalc(r.a0.w, r.a1.w, r.a2.w, r.a3.w, r.ta.w, r.vA, wa.w, wb.w);
        ((uint4*)Pa)[rA * 40 + cA] = wa;   // 16-B lane stride: conflict-free
        ((uint4*)Pb)[rA * 40 + cA] = wb;
        if (hasB) {
            qcalc(r.b0.x, r.b1.x, r.b2.x, r.b3.x, r.tb.x, r.vB, wa.x, wb.x);
            qcalc(r.b0.y, r.b1.y, r.b2.y, r.b3.y, r.tb.y, r.vB, wa.y, wb.y);
            qcalc(r.b0.z, r.b1.z, r.b2.z, r.b3.z, r.tb.z, r.vB, wa.z, wb.z);
            qcalc(r.b0.w, r.b1.w, r.b2.w, r.b3.w, r.tb.w, r.vB, wa.w, wb.w);
            ((uint4*)Pa)[rB * 40 + cB] = wa;
            ((uint4*)Pb)[rB * 40 + cB] = wb;
        }
    };

    auto compute_band = [&](const unsigned int* Pa, const unsigned int* Pb) {
        float a = 0.f;
        if (tid < NW) {
            int am = tid;
            int al = (tid > 0)      ? tid - 1 : ZCELL;
            int ar = (tid < NW - 1) ? tid + 1 : ZCELL;
            const int il = (tid > 0)      ? NW : 0;
            const int ir = (tid < NW - 1) ? NW : 0;

            const __half2 two = __floats2half2_rn(2.f, 2.f);
            const __half2 hz  = __floats2half2_rn(0.f, 0.f);
            __half2 smmA = hz, smA = hz, dmmA = hz, dmA = hz;
            __half2 smmB = hz, smB = hz, dmmB = hz, dmB = hz;

#define CLS(P, smm, sm, dmm, dm)                                          \
            do {                                                          \
                const __half2 l = ld_h2(P, al);                           \
                const __half2 m = ld_h2(P, am);                           \
                const __half2 r = ld_h2(P, ar);                           \
                const __half2 sn = __hadd2(__hfma2(m, two, l), r);        \
                const __half2 dn = __hsub2(r, l);                         \
                if (t >= 2) {                                             \
                    const __half2 gx = __hadd2(__hfma2(dm, two, dmm), dn);\
                    const __half2 gy = __hsub2(sn, smm);                  \
                    const __half2 rs = __hfma2(__hmul2(gy, gy), two,      \
                                               __hmul2(gx, gx));          \
                    a += __low2float(rs) + __high2float(rs);              \
                }                                                         \
                smm = sm; sm = sn; dmm = dm; dm = dn;                     \
            } while (0)

            #pragma unroll
            for (int t = 0; t < SR; ++t) {
                CLS(Pa, smmA, smA, dmmA, dmA);
                CLS(Pb, smmB, smB, dmmB, dmB);
                am += NW; al += il; ar += ir;
            }
#undef CLS
        }
        return a;
    };

    // ---- Pipelined M-band loop, double-buffered LDS ----
    if (tid == 0) {
        pa[0][ZCELL] = 0u; pb[0][ZCELL] = 0u;   // x-boundary guard cells
        pa[1][ZCELL] = 0u; pb[1][ZCELL] = 0u;
    }
    Regs r0 = load_band(yseg);
    stage_band(r0, pa[0], pb[0]);
    __syncthreads();

    float acc = 0.f;
    #pragma unroll
    for (int i = 0; i < M; ++i) {
        Regs rn;
        if (i + 1 < M) rn = load_band(yseg + (i + 1) * TH);  // issue early
        acc += compute_band(pa[i & 1], pb[i & 1]);           // hides latency
        if (i + 1 < M) stage_band(rn, pa[(i + 1) & 1], pb[(i + 1) & 1]);
        __syncthreads();   // separates {compute i, stage i+1} from next iter
    }

    // ---- Block reduction -> ONE PLAIN STORE per block (no atomics) ----
    #pragma unroll
    for (int off = 32; off > 0; off >>= 1)
        acc += __shfl_down(acc, off, 64);
    if ((tid & 63) == 0) wsum[tid >> 6] = acc;
    __syncthreads();
    if (tid == 0) {
        part[blockIdx.y * SEG + blockIdx.x] =
            wsum[0] + wsum[1] + wsum[2] + wsum[3];
    }
}

__global__ __launch_bounds__(256) void reduce_partials_kernel(
    const float* __restrict__ part, float* __restrict__ out)
{
    const int tid = threadIdx.x;
    float s = 0.f;
    #pragma unroll
    for (int i = 0; i < NPART / 256; ++i)     // 3 loads, coalesced
        s += part[tid + i * 256];
    #pragma unroll
    for (int off = 32; off > 0; off >>= 1)
        s += __shfl_down(s, off, 64);
    __shared__ float wsum[4];
    if ((tid & 63) == 0) wsum[tid >> 6] = s;
    __syncthreads();
    if (tid == 0)
        out[0] = (wsum[0] + wsum[1] + wsum[2] + wsum[3]) * SCALE;
}

extern "C" void kernel_launch(void* const* d_in, const int* in_sizes, int n_in,
                              void* d_out, int out_size, void* d_ws, size_t ws_size,
                              hipStream_t stream) {
    const float* pred   = (const float*)d_in[0];
    const int*   target = (const int*)d_in[1];
    float*       out    = (float*)d_out;
    float*       part   = (float*)d_ws;      // NPART*4 = 3 KB of scratch

    dim3 grid(SEG, NB * ND);   // 4 x 192 = 768 blocks, M=5 bands each
    boundary_loss_kernel<<<grid, 256, 0, stream>>>(pred, target, part);
    reduce_partials_kernel<<<1, 256, 0, stream>>>(part, out);
}